// Round 5
// baseline (201.055 us; speedup 1.0000x reference)
//
#include <hip/hip_runtime.h>

#define NX 512
#define NY 512
#define XY (NX * NY)

typedef float f4 __attribute__((ext_vector_type(4)));

#define GLOBAL_AS __attribute__((address_space(1)))
#define LDS_AS    __attribute__((address_space(3)))

// 8-row-strip independent-block version (r3 structure, taller strips).
// Read amplification drops 2.0x -> 1.5x (10 staged + 2 register-halo rows per
// 8 output rows): total traffic 294 -> 245 MB at the measured ~4.95 TB/s
// effective service rate. 2048 single-shot blocks (XCD-swizzled), 512 threads,
// each thread owns a 2-row x 4-col output tile. LDS = 60 KB s + 20 KB b =
// 80 KB -> exactly 2 blocks/CU (same co-residency as r3, which sustained the
// rate). 2 barriers/block. launch_bounds(512,4): cap 128 >= ~105 peak VGPR.
__global__ __launch_bounds__(512, 4) void psi11t_kernel(
    const float* __restrict__ s,
    const float* __restrict__ t,
    const float* __restrict__ c0,
    float* __restrict__ out)
{
    __shared__ __align__(16) float s_lds[3 * 10 * NY]; // [c][sr][y], sr <-> x0-1+sr
    __shared__ __align__(16) float b_lds[10 * NY];     // [br][y],   br <-> x0-1+br

    // XCD swizzle: each XCD (D%8) gets 256 consecutive logical ids = 4 whole
    // batches -> halo reuse stays within one XCD's L2. 2048 % 8 == 0: bijective.
    const int D   = blockIdx.x;               // 2048 blocks
    const int gid = (D & 7) * 256 + (D >> 3);
    const int bidx  = gid >> 6;               // 32 batches
    const int strip = gid & 63;               // 64 strips of 8 rows
    const int x0  = strip * 8;
    const int tid = threadIdx.x;
    const int r   = tid >> 7;                 // 0..3: row-pair group
    const int yb  = (tid & 127) * 4;
    const int ybm = (yb + NY - 4) & (NY - 1); // aligned f4 at y-4 (wrap)
    const int ybp = (yb + 4) & (NY - 1);      // aligned f4 at y+4 (wrap)
    const bool lo256 = (tid < 256);

    const float* sb = s + (size_t)bidx * 3 * XY;

    // ---- Phase 1: stage s rows x0-1..x0+8 (10 rows x 3 comps = 60 KB) via
    // global_load_lds. Chunk k = tid + q*512; ru = k>>7 = c*10 + sr (0..29).
    #pragma unroll
    for (int q = 0; q < 7; ++q) {
        const int k  = tid + q * 512;
        const int ru = k >> 7;                // r + 4q in 0..27
        const int c  = (ru >= 20) ? 2 : ((ru >= 10) ? 1 : 0);
        const int sr = ru - 10 * c;
        const int xg = (x0 - 1 + sr + NX) & (NX - 1);
        __builtin_amdgcn_global_load_lds(
            (const GLOBAL_AS void*)(sb + (size_t)c * XY + (size_t)xg * NY + (k & 127) * 4),
            (LDS_AS void*)&s_lds[(size_t)k * 4], 16, 0, 0);
    }
    if (lo256) {                              // ru = 28,29 -> c=2, sr=8,9
        const int k  = tid + 7 * 512;
        const int sr = (k >> 7) - 20;
        const int xg = (x0 - 1 + sr) & (NX - 1);
        __builtin_amdgcn_global_load_lds(
            (const GLOBAL_AS void*)(sb + (size_t)2 * XY + (size_t)xg * NY + (k & 127) * 4),
            (LDS_AS void*)&s_lds[(size_t)k * 4], 16, 0, 0);
    }

    // Outer halo rows (x0-2, x0+9) in registers; dead after phase 2.
    f4 ge[3];
    if (lo256) {
        const int xe = (tid < 128) ? ((x0 - 2 + NX) & (NX - 1)) : ((x0 + 9) & (NX - 1));
        const float* re = sb + (size_t)xe * NY + yb;
        #pragma unroll
        for (int c = 0; c < 3; ++c) ge[c] = *(const f4*)(re + (size_t)c * XY);
    }

    const float coeff = 2.0f * t[0] * c0[0];
    __syncthreads();                          // A: s_lds ready (vmcnt drained)

    // ---- Phase 2: b rows. Group r computes b rows 2r+1, 2r+2 (centers
    // x0+2r, x0+2r+1); retains s-fragments for phase 3.
    f4 up[3], ce0[3], ce1[3], dn[3];
    float pv30[3], nx00[3], pv31[3], nx01[3];
    f4 bc0 = {0.f, 0.f, 0.f, 0.f};
    f4 bc1 = {0.f, 0.f, 0.f, 0.f};
    #pragma unroll
    for (int c = 0; c < 3; ++c) {
        const float* S0 = &s_lds[(c * 10 + 2 * r + 1) * NY];
        const float* S1 = &s_lds[(c * 10 + 2 * r + 2) * NY];
        up[c]  = *(const f4*)&s_lds[(c * 10 + 2 * r) * NY + yb];
        ce0[c] = *(const f4*)(S0 + yb);
        ce1[c] = *(const f4*)(S1 + yb);
        dn[c]  = *(const f4*)&s_lds[(c * 10 + 2 * r + 3) * NY + yb];
        const f4 pv0 = *(const f4*)(S0 + ybm);
        const f4 nx0 = *(const f4*)(S0 + ybp);
        const f4 pv1 = *(const f4*)(S1 + ybm);
        const f4 nx1 = *(const f4*)(S1 + ybp);
        pv30[c] = pv0[3]; nx00[c] = nx0[0];
        pv31[c] = pv1[3]; nx01[c] = nx1[0];
        const f4 shl0 = {pv0[3], ce0[c][0], ce0[c][1], ce0[c][2]};
        const f4 shr0 = {ce0[c][1], ce0[c][2], ce0[c][3], nx0[0]};
        const f4 shl1 = {pv1[3], ce1[c][0], ce1[c][1], ce1[c][2]};
        const f4 shr1 = {ce1[c][1], ce1[c][2], ce1[c][3], nx1[0]};
        bc0 += ce0[c] * (up[c] + ce1[c] + shl0 + shr0);
        bc1 += ce1[c] * (ce0[c] + dn[c] + shl1 + shr1);
    }
    *(f4*)&b_lds[(2 * r + 1) * NY + yb] = bc0;
    *(f4*)&b_lds[(2 * r + 2) * NY + yb] = bc1;

    // halo b rows 0 (x=x0-1) and 9 (x=x0+8); wave-uniform branches.
    if (lo256) {
        const int br = (tid < 128) ? 0 : 9;
        const int ro = (tid < 128) ? 1 : 8;
        f4 acc = {0.f, 0.f, 0.f, 0.f};
        #pragma unroll
        for (int c = 0; c < 3; ++c) {
            const float* SC = &s_lds[(c * 10 + br) * NY];
            const f4 c2 = *(const f4*)(SC + yb);
            const f4 p2 = *(const f4*)(SC + ybm);
            const f4 n2 = *(const f4*)(SC + ybp);
            const f4 ot = *(const f4*)&s_lds[(c * 10 + ro) * NY + yb];
            const f4 sl  = {p2[3], c2[0], c2[1], c2[2]};
            const f4 sr2 = {c2[1], c2[2], c2[3], n2[0]};
            acc += c2 * (ge[c] + ot + sl + sr2);
        }
        *(f4*)&b_lds[br * NY + yb] = acc;
    }
    __syncthreads();                          // B: b_lds ready

    // ---- Phase 3: output rows x0+2r (ce0/bc0) and x0+2r+1 (ce1/bc1).
    // Vertical b neighbors between the pair come from registers (bc0/bc1).
    const f4 bu0 = *(const f4*)&b_lds[(2 * r) * NY + yb];
    const f4 bd1 = *(const f4*)&b_lds[(2 * r + 3) * NY + yb];
    const float* B0 = &b_lds[(2 * r + 1) * NY];
    const float* B1 = &b_lds[(2 * r + 2) * NY];
    const f4 bp0 = *(const f4*)(B0 + ybm);
    const f4 bn0 = *(const f4*)(B0 + ybp);
    const f4 bp1 = *(const f4*)(B1 + ybm);
    const f4 bn1 = *(const f4*)(B1 + ybp);
    const f4 bshl0 = {bp0[3], bc0[0], bc0[1], bc0[2]};
    const f4 bshr0 = {bc0[1], bc0[2], bc0[3], bn0[0]};
    const f4 bshl1 = {bp1[3], bc1[0], bc1[1], bc1[2]};
    const f4 bshr1 = {bc1[1], bc1[2], bc1[3], bn1[0]};

    f4 G0[3], G1[3];
    #pragma unroll
    for (int c = 0; c < 3; ++c) {
        const f4 shl0 = {pv30[c], ce0[c][0], ce0[c][1], ce0[c][2]};
        const f4 shr0 = {ce0[c][1], ce0[c][2], ce0[c][3], nx00[c]};
        const f4 shl1 = {pv31[c], ce1[c][0], ce1[c][1], ce1[c][2]};
        const f4 shr1 = {ce1[c][1], ce1[c][2], ce1[c][3], nx01[c]};
        const f4 Fs0 = up[c] + ce1[c] + shl0 + shr0;
        const f4 Fs1 = ce0[c] + dn[c] + shl1 + shr1;
        G0[c] = Fs0 * bc0 + up[c]  * bu0 + ce1[c] * bc1 + shl0 * bshl0 + shr0 * bshr0;
        G1[c] = Fs1 * bc1 + ce0[c] * bc0 + dn[c]  * bd1 + shl1 * bshl1 + shr1 * bshr1;
    }

    const f4 o00 = (ce0[1] * G0[2] - ce0[2] * G0[1]) * coeff;
    const f4 o01 = (ce0[2] * G0[0] - ce0[0] * G0[2]) * coeff;
    const f4 o02 = (ce0[0] * G0[1] - ce0[1] * G0[0]) * coeff;
    const f4 o10 = (ce1[1] * G1[2] - ce1[2] * G1[1]) * coeff;
    const f4 o11 = (ce1[2] * G1[0] - ce1[0] * G1[2]) * coeff;
    const f4 o12 = (ce1[0] * G1[1] - ce1[1] * G1[0]) * coeff;

    float* ob = out + (size_t)bidx * 3 * XY + (size_t)(x0 + 2 * r) * NY + yb;
    __builtin_nontemporal_store(o00, (f4*)ob);
    __builtin_nontemporal_store(o01, (f4*)(ob + XY));
    __builtin_nontemporal_store(o02, (f4*)(ob + 2 * XY));
    __builtin_nontemporal_store(o10, (f4*)(ob + NY));
    __builtin_nontemporal_store(o11, (f4*)(ob + XY + NY));
    __builtin_nontemporal_store(o12, (f4*)(ob + 2 * XY + NY));
}

extern "C" void kernel_launch(void* const* d_in, const int* in_sizes, int n_in,
                              void* d_out, int out_size, void* d_ws, size_t ws_size,
                              hipStream_t stream) {
    const float* s  = (const float*)d_in[0];
    const float* t  = (const float*)d_in[1];
    const float* c0 = (const float*)d_in[2];
    float* out = (float*)d_out;

    psi11t_kernel<<<2048, 512, 0, stream>>>(s, t, c0, out);
}

// Round 6
// 180.441 us; speedup vs baseline: 1.1142x; 1.1142x over previous
//
#include <hip/hip_runtime.h>

#define NX 512
#define NY 512
#define XY (NX * NY)

typedef float f4 __attribute__((ext_vector_type(4)));

#define GLOBAL_AS __attribute__((address_space(1)))
#define LDS_AS    __attribute__((address_space(3)))

// 8-row-strip, NO-retention version (r5 minus the spill vector).
// Read amplification 1.5x (10 staged + 2 register-halo rows per 8 output
// rows). Phase 3 re-reads s from LDS (proven free in r3 vs r1: <=1%) and
// processes its two output rows SEQUENTIALLY to halve peak live VGPRs (~70).
// Only bc0/bc1 (8 regs) are retained across barrier B.
// 2048 single-shot XCD-swizzled blocks x 512 threads; LDS 60 KB s + 20 KB b
// = 80 KB -> 2 blocks/CU; 2 barriers/block; all LDS reads aligned b128.
// Tripwire from r2/r5: WRITE_SIZE must be ~98.3 MB; more means spill.
__global__ __launch_bounds__(512, 4) void psi11t_kernel(
    const float* __restrict__ s,
    const float* __restrict__ t,
    const float* __restrict__ c0,
    float* __restrict__ out)
{
    __shared__ __align__(16) float s_lds[3 * 10 * NY]; // [c][sr][y], sr <-> x0-1+sr
    __shared__ __align__(16) float b_lds[10 * NY];     // [br][y],   br <-> x0-1+br

    // XCD swizzle: each XCD (D%8) gets 256 consecutive logical ids = 4 whole
    // batches. 2048 % 8 == 0 -> bijective.
    const int D   = blockIdx.x;               // 2048 blocks
    const int gid = (D & 7) * 256 + (D >> 3);
    const int bidx  = gid >> 6;               // 32 batches
    const int strip = gid & 63;               // 64 strips of 8 rows
    const int x0  = strip * 8;
    const int tid = threadIdx.x;
    const int r   = tid >> 7;                 // 0..3: row-pair group
    const int yb  = (tid & 127) * 4;
    const int ybm = (yb + NY - 4) & (NY - 1); // aligned f4 at y-4 (wrap)
    const int ybp = (yb + 4) & (NY - 1);      // aligned f4 at y+4 (wrap)
    const bool lo256 = (tid < 256);

    const float* sb = s + (size_t)bidx * 3 * XY;

    // ---- Phase 1: stage s rows x0-1..x0+8 (10 rows x 3 comps = 60 KB) via
    // global_load_lds. Chunk k = tid + q*512; ru = k>>7 = c*10 + sr (0..29).
    #pragma unroll
    for (int q = 0; q < 7; ++q) {
        const int k  = tid + q * 512;
        const int ru = k >> 7;                // 0..27
        const int c  = (ru >= 20) ? 2 : ((ru >= 10) ? 1 : 0);
        const int sr = ru - 10 * c;
        const int xg = (x0 - 1 + sr + NX) & (NX - 1);
        __builtin_amdgcn_global_load_lds(
            (const GLOBAL_AS void*)(sb + (size_t)c * XY + (size_t)xg * NY + (k & 127) * 4),
            (LDS_AS void*)&s_lds[(size_t)k * 4], 16, 0, 0);
    }
    if (lo256) {                              // ru = 28,29 -> c=2, sr=8,9
        const int k  = tid + 7 * 512;
        const int sr = (k >> 7) - 20;
        const int xg = (x0 - 1 + sr) & (NX - 1);
        __builtin_amdgcn_global_load_lds(
            (const GLOBAL_AS void*)(sb + (size_t)2 * XY + (size_t)xg * NY + (k & 127) * 4),
            (LDS_AS void*)&s_lds[(size_t)k * 4], 16, 0, 0);
    }

    // Outer halo rows (x0-2, x0+9) in registers; dead after phase 2.
    f4 ge[3];
    if (lo256) {
        const int xe = (tid < 128) ? ((x0 - 2 + NX) & (NX - 1)) : ((x0 + 9) & (NX - 1));
        const float* re = sb + (size_t)xe * NY + yb;
        #pragma unroll
        for (int c = 0; c < 3; ++c) ge[c] = *(const f4*)(re + (size_t)c * XY);
    }

    const float coeff = 2.0f * t[0] * c0[0];
    __syncthreads();                          // A: s_lds ready (vmcnt drained)

    // ---- Phase 2: group r computes b rows 2r+1, 2r+2 (centers x0+2r,
    // x0+2r+1). No s retention; only bc0/bc1 survive to phase 3.
    f4 bc0 = {0.f, 0.f, 0.f, 0.f};
    f4 bc1 = {0.f, 0.f, 0.f, 0.f};
    #pragma unroll
    for (int c = 0; c < 3; ++c) {
        const float* S0 = &s_lds[(c * 10 + 2 * r + 1) * NY];
        const float* S1 = &s_lds[(c * 10 + 2 * r + 2) * NY];
        const f4 up  = *(const f4*)&s_lds[(c * 10 + 2 * r) * NY + yb];
        const f4 ce0 = *(const f4*)(S0 + yb);
        const f4 ce1 = *(const f4*)(S1 + yb);
        const f4 dn  = *(const f4*)&s_lds[(c * 10 + 2 * r + 3) * NY + yb];
        const f4 pv0 = *(const f4*)(S0 + ybm);
        const f4 nx0 = *(const f4*)(S0 + ybp);
        const f4 pv1 = *(const f4*)(S1 + ybm);
        const f4 nx1 = *(const f4*)(S1 + ybp);
        const f4 shl0 = {pv0[3], ce0[0], ce0[1], ce0[2]};
        const f4 shr0 = {ce0[1], ce0[2], ce0[3], nx0[0]};
        const f4 shl1 = {pv1[3], ce1[0], ce1[1], ce1[2]};
        const f4 shr1 = {ce1[1], ce1[2], ce1[3], nx1[0]};
        bc0 += ce0 * (up + ce1 + shl0 + shr0);
        bc1 += ce1 * (ce0 + dn + shl1 + shr1);
    }
    *(f4*)&b_lds[(2 * r + 1) * NY + yb] = bc0;
    *(f4*)&b_lds[(2 * r + 2) * NY + yb] = bc1;

    // halo b rows 0 (x=x0-1) and 9 (x=x0+8); wave-uniform branches.
    if (lo256) {
        const int br = (tid < 128) ? 0 : 9;
        const int ro = (tid < 128) ? 1 : 8;
        f4 acc = {0.f, 0.f, 0.f, 0.f};
        #pragma unroll
        for (int c = 0; c < 3; ++c) {
            const float* SC = &s_lds[(c * 10 + br) * NY];
            const f4 c2 = *(const f4*)(SC + yb);
            const f4 p2 = *(const f4*)(SC + ybm);
            const f4 n2 = *(const f4*)(SC + ybp);
            const f4 ot = *(const f4*)&s_lds[(c * 10 + ro) * NY + yb];
            const f4 sl  = {p2[3], c2[0], c2[1], c2[2]};
            const f4 sr2 = {c2[1], c2[2], c2[3], n2[0]};
            acc += c2 * (ge[c] + ot + sl + sr2);
        }
        *(f4*)&b_lds[br * NY + yb] = acc;
    }
    __syncthreads();                          // B: b_lds ready

    float* ob = out + (size_t)bidx * 3 * XY + (size_t)(x0 + 2 * r) * NY + yb;

    // ---- Phase 3a: output row x0+2r (center s-row 2r+1, b center bc0) ----
    {
        const float* B = &b_lds[(2 * r + 1) * NY];
        const f4 bu = *(const f4*)&b_lds[(2 * r) * NY + yb];
        const f4 bp = *(const f4*)(B + ybm);
        const f4 bn = *(const f4*)(B + ybp);
        const f4 bshl = {bp[3], bc0[0], bc0[1], bc0[2]};
        const f4 bshr = {bc0[1], bc0[2], bc0[3], bn[0]};

        f4 G[3], cen[3];
        #pragma unroll
        for (int c = 0; c < 3; ++c) {
            const float* SC = &s_lds[(c * 10 + 2 * r + 1) * NY];
            const f4 up = *(const f4*)&s_lds[(c * 10 + 2 * r) * NY + yb];
            const f4 ce = *(const f4*)(SC + yb);
            const f4 dn = *(const f4*)&s_lds[(c * 10 + 2 * r + 2) * NY + yb];
            const f4 pv = *(const f4*)(SC + ybm);
            const f4 nx = *(const f4*)(SC + ybp);
            const f4 shl = {pv[3], ce[0], ce[1], ce[2]};
            const f4 shr = {ce[1], ce[2], ce[3], nx[0]};
            const f4 Fs = up + dn + shl + shr;
            G[c] = Fs * bc0 + up * bu + dn * bc1 + shl * bshl + shr * bshr;
            cen[c] = ce;
        }
        const f4 o0 = (cen[1] * G[2] - cen[2] * G[1]) * coeff;
        const f4 o1 = (cen[2] * G[0] - cen[0] * G[2]) * coeff;
        const f4 o2 = (cen[0] * G[1] - cen[1] * G[0]) * coeff;
        __builtin_nontemporal_store(o0, (f4*)ob);
        __builtin_nontemporal_store(o1, (f4*)(ob + XY));
        __builtin_nontemporal_store(o2, (f4*)(ob + 2 * XY));
    }

    // ---- Phase 3b: output row x0+2r+1 (center s-row 2r+2, b center bc1) ----
    {
        const float* B = &b_lds[(2 * r + 2) * NY];
        const f4 bd = *(const f4*)&b_lds[(2 * r + 3) * NY + yb];
        const f4 bp = *(const f4*)(B + ybm);
        const f4 bn = *(const f4*)(B + ybp);
        const f4 bshl = {bp[3], bc1[0], bc1[1], bc1[2]};
        const f4 bshr = {bc1[1], bc1[2], bc1[3], bn[0]};

        f4 G[3], cen[3];
        #pragma unroll
        for (int c = 0; c < 3; ++c) {
            const float* SC = &s_lds[(c * 10 + 2 * r + 2) * NY];
            const f4 up = *(const f4*)&s_lds[(c * 10 + 2 * r + 1) * NY + yb];
            const f4 ce = *(const f4*)(SC + yb);
            const f4 dn = *(const f4*)&s_lds[(c * 10 + 2 * r + 3) * NY + yb];
            const f4 pv = *(const f4*)(SC + ybm);
            const f4 nx = *(const f4*)(SC + ybp);
            const f4 shl = {pv[3], ce[0], ce[1], ce[2]};
            const f4 shr = {ce[1], ce[2], ce[3], nx[0]};
            const f4 Fs = up + dn + shl + shr;
            G[c] = Fs * bc1 + up * bc0 + dn * bd + shl * bshl + shr * bshr;
            cen[c] = ce;
        }
        const f4 o0 = (cen[1] * G[2] - cen[2] * G[1]) * coeff;
        const f4 o1 = (cen[2] * G[0] - cen[0] * G[2]) * coeff;
        const f4 o2 = (cen[0] * G[1] - cen[1] * G[0]) * coeff;
        __builtin_nontemporal_store(o0, (f4*)(ob + NY));
        __builtin_nontemporal_store(o1, (f4*)(ob + XY + NY));
        __builtin_nontemporal_store(o2, (f4*)(ob + 2 * XY + NY));
    }
}

extern "C" void kernel_launch(void* const* d_in, const int* in_sizes, int n_in,
                              void* d_out, int out_size, void* d_ws, size_t ws_size,
                              hipStream_t stream) {
    const float* s  = (const float*)d_in[0];
    const float* t  = (const float*)d_in[1];
    const float* c0 = (const float*)d_in[2];
    float* out = (float*)d_out;

    psi11t_kernel<<<2048, 512, 0, stream>>>(s, t, c0, out);
}